// Round 7
// baseline (91.162 us; speedup 1.0000x reference)
//
#include <hip/hip_runtime.h>

// CapsuleConv2d, MI355X gfx950. ALL I/O FP32.
// B=2, C_in=128 (G=8 x M=16), 32x32, 3x3 pad 1, O=16, L=16 -> C_out=256.
// k-means (dot) routing 3 iters + squash.
//
// v14: v13 evidence says phase 2 is LATENCY-bound (v13 == v9 despite -450
// VALU/wave). Phase-2 parallelism was capped at 16 waves/CU = pixels/CU
// (LDS 9.8KB/pixel). v14 splits each pixel's routing across TWO waves (by
// o2): block = 4 pixels x 512 threads, same 38.25KB LDS, 4 blocks/CU ->
// 32 waves/CU (HW cap), per-thread chain ~2x shorter (2-3 rows, 2-3 exps).
//  - phase 1: v13-verbatim, executed by waves 0-3 (waves 4-7 just barrier).
//  - phase 2: lane = jh(bit5) x sc(bits0-4); n-reduce = dpp16+xor16 (red32),
//    jh (16-l dot) combine via __shfl_xor(.,32). Rows per thread:
//    {sc, sc+32, sc+64 if sc<8}.
//  - prep2 (xP/Wbf pre-pack) and fallback unchanged from v13.

typedef float v2f __attribute__((ext_vector_type(2)));
typedef int   i4  __attribute__((ext_vector_type(4)));
typedef short bh8 __attribute__((ext_vector_type(8)));
typedef float f16v __attribute__((ext_vector_type(16)));

#define STR 34                          // u LDS row stride (floats)
#define WBF_ELEMS 73728                 // Wbf u16 count (144 KB)

#define DPP_ADD(a, ctrl)                                                     \
  a += __int_as_float(__builtin_amdgcn_update_dpp(                           \
          0, __float_as_int(a), ctrl, 0xF, 0xF, true))

__device__ __forceinline__ float dpp_add16(float x) {
    // row_ror chain: all 16 lanes of each row end with the 16-lane sum
    float s = x;
    DPP_ADD(s, 0x128); DPP_ADD(s, 0x124); DPP_ADD(s, 0x122); DPP_ADD(s, 0x121);
    return s;
}

__device__ __forceinline__ float swz16_add(float x) {
    // x + value from lane^16 within each 32-lane group
    int y = __builtin_amdgcn_ds_swizzle(__float_as_int(x), 0x401F);
    return x + __int_as_float(y);
}

__device__ __forceinline__ float red32(float x) {
    // full 32-lane-group broadcast-sum (lane bits 0-4)
    return swz16_add(dpp_add16(x));
}

__device__ __forceinline__ float xor32_add(float x) {
    // x + value from lane^32 (cross half-wave)
    return x + __shfl_xor(x, 32, 64);
}

__device__ __forceinline__ float frcp(float x) {
    return __builtin_amdgcn_rcpf(x);
}

__device__ __forceinline__ v2f pkfma(v2f a, v2f b, v2f c) {
    return __builtin_elementwise_fma(a, b, c);
}

// ---- prep2 (v12/v13 verbatim): blk<64 -> xP pack; blk>=64 -> Wbf pack ----
__global__ __launch_bounds__(256)
void prep2_kernel(const float* __restrict__ x, const float* __restrict__ W,
                  i4* __restrict__ xP, unsigned short* __restrict__ Wbf) {
    const int blk = blockIdx.x;
    const int tid = threadIdx.x;
    if (blk < 64) {
        __shared__ float xs[128 * 33];
        const int b = blk >> 5, h = blk & 31;
        const float* xb = x + b * (128 * 32 * 32) + h * 32;
        #pragma unroll
        for (int k = 0; k < 16; ++k) {
            int idx = k * 256 + tid;
            int c = idx >> 5, w = idx & 31;
            xs[c * 33 + w] = xb[c * 1024 + w];
        }
        __syncthreads();
        i4* xo = xP + (b * 32 + h) * 1024;
        #pragma unroll
        for (int it = 0; it < 4; ++it) {
            int slot = it * 256 + tid;          // = w*32 + gl*4 + hf*2 + s
            int s  = slot & 1;
            int hf = (slot >> 1) & 1;
            int gl = (slot >> 2) & 7;
            int w  = slot >> 5;
            int c0 = gl * 16 + hf * 8;
            float f0 = xs[(c0 + 0) * 33 + w], f1 = xs[(c0 + 1) * 33 + w];
            float f2 = xs[(c0 + 2) * 33 + w], f3 = xs[(c0 + 3) * 33 + w];
            float f4 = xs[(c0 + 4) * 33 + w], f5 = xs[(c0 + 5) * 33 + w];
            float f6 = xs[(c0 + 6) * 33 + w], f7 = xs[(c0 + 7) * 33 + w];
            unsigned b0 = __float_as_uint(f0), b1 = __float_as_uint(f1);
            unsigned b2 = __float_as_uint(f2), b3 = __float_as_uint(f3);
            unsigned b4 = __float_as_uint(f4), b5 = __float_as_uint(f5);
            unsigned b6 = __float_as_uint(f6), b7 = __float_as_uint(f7);
            i4 pk;
            if (s == 0) {
                pk.x = (int)((b0 >> 16) | (b1 & 0xFFFF0000u));
                pk.y = (int)((b2 >> 16) | (b3 & 0xFFFF0000u));
                pk.z = (int)((b4 >> 16) | (b5 & 0xFFFF0000u));
                pk.w = (int)((b6 >> 16) | (b7 & 0xFFFF0000u));
            } else {
                unsigned l0 = __float_as_uint(f0 - __uint_as_float(b0 & 0xFFFF0000u));
                unsigned l1 = __float_as_uint(f1 - __uint_as_float(b1 & 0xFFFF0000u));
                unsigned l2 = __float_as_uint(f2 - __uint_as_float(b2 & 0xFFFF0000u));
                unsigned l3 = __float_as_uint(f3 - __uint_as_float(b3 & 0xFFFF0000u));
                unsigned l4 = __float_as_uint(f4 - __uint_as_float(b4 & 0xFFFF0000u));
                unsigned l5 = __float_as_uint(f5 - __uint_as_float(b5 & 0xFFFF0000u));
                unsigned l6 = __float_as_uint(f6 - __uint_as_float(b6 & 0xFFFF0000u));
                unsigned l7 = __float_as_uint(f7 - __uint_as_float(b7 & 0xFFFF0000u));
                pk.x = (int)((l0 >> 16) | (l1 & 0xFFFF0000u));
                pk.y = (int)((l2 >> 16) | (l3 & 0xFFFF0000u));
                pk.z = (int)((l4 >> 16) | (l5 & 0xFFFF0000u));
                pk.w = (int)((l6 >> 16) | (l7 & 0xFFFF0000u));
            }
            xo[slot] = pk;
        }
    } else {
        int idx = (blk - 64) * 256 + tid;     // 0..73727
        int j  = idx & 7;
        int L  = (idx >> 3) & 63;
        int s  = (idx >> 9) & 1;
        int tt = (idx >> 10) & 7;
        int ij = idx >> 13;
        int k  = (L >> 5) * 8 + j;
        int t  = tt * 32 + (L & 31);
        float wv = W[(t * 16 + k) * 9 + ij];
        unsigned bits = __float_as_uint(wv);
        unsigned hib  = bits & 0xFFFF0000u;
        unsigned short val;
        if (s == 0) val = (unsigned short)(hib >> 16);
        else {
            float lo = wv - __uint_as_float(hib);
            val = (unsigned short)(__float_as_uint(lo) >> 16);
        }
        Wbf[idx] = val;
    }
}

// ---- phase-1 macros (v13 verbatim) ----
#define ALOADIJ(AH, AL, OK, IJ) {                                            \
    const int di = (IJ) / 3, dj = (IJ) % 3;                                  \
    const int hh = h + di - 1;                                               \
    const bool hok = (unsigned)hh < 32u;                                     \
    const int hhc = hok ? hh : 0;                                            \
    const int ww = w0 + pl + dj - 1;                                         \
    OK = hok && ((unsigned)ww < 32u);                                        \
    const int wwc = OK ? ww : 0;                                             \
    const int slot = (((bb * 32 + hhc) * 32 + wwc) * 8 + gl) * 2 + half;     \
    AH = xpi4[slot * 2]; AL = xpi4[slot * 2 + 1]; }

#define BLOADIJ(BH, BL, IJ) {                                                \
    BH = bfr[((IJ) * 8 + tt) * 128 + lane];                                  \
    BL = bfr[((IJ) * 8 + tt) * 128 + 64 + lane]; }

#define CWR(REG, IJ)                                                         \
    uLds[wroff + STR * ((((REG) >> 2) * 72) + (((REG) & 3) * 9) + (IJ))] =   \
        acc[(REG)];

#define PROCIJ(AH, AL, OK, BH, BL, IJ) {                                     \
    const i4 z_ = {0, 0, 0, 0};                                              \
    i4 ah_ = OK ? AH : z_;                                                   \
    i4 al_ = OK ? AL : z_;                                                   \
    bh8 aHi = __builtin_bit_cast(bh8, ah_);                                  \
    bh8 aLo = __builtin_bit_cast(bh8, al_);                                  \
    bh8 bHi = __builtin_bit_cast(bh8, BH);                                   \
    bh8 bLo = __builtin_bit_cast(bh8, BL);                                   \
    f16v acc = {0.f,0.f,0.f,0.f,0.f,0.f,0.f,0.f,                             \
                0.f,0.f,0.f,0.f,0.f,0.f,0.f,0.f};                            \
    acc = __builtin_amdgcn_mfma_f32_32x32x16_bf16(aHi, bLo, acc, 0, 0, 0);   \
    acc = __builtin_amdgcn_mfma_f32_32x32x16_bf16(aLo, bHi, acc, 0, 0, 0);   \
    acc = __builtin_amdgcn_mfma_f32_32x32x16_bf16(aHi, bHi, acc, 0, 0, 0);   \
    CWR(0, IJ)  CWR(1, IJ)  CWR(2, IJ)  CWR(3, IJ)                           \
    CWR(4, IJ)  CWR(5, IJ)  CWR(6, IJ)  CWR(7, IJ)                           \
    CWR(8, IJ)  CWR(9, IJ)  CWR(10, IJ) CWR(11, IJ)                          \
    CWR(12, IJ) CWR(13, IJ) CWR(14, IJ) CWR(15, IJ) }

// ---- phase-2 macros (v14: 2-3 rows/thread, red32 over sc, xor32 for jh) ----
#define LROWV(U0_, U1_, U2_, U3_, OFF)                                       \
  { const v2f* r2_ = (const v2f*)(rb + (OFF) * STR);                         \
    U0_ = r2_[0]; U1_ = r2_[1]; U2_ = r2_[2]; U3_ = r2_[3]; }

#define DOTV(UK0, UK1, UK2, UK3)                                             \
  ({ v2f d_ = UK0 * V0;                                                      \
     d_ = pkfma(UK1, V1, d_); d_ = pkfma(UK2, V2, d_);                       \
     d_ = pkfma(UK3, V3, d_); xor32_add(d_.x + d_.y); })

#define MEANJ(J)                                                             \
  { v2f s_ = (U0##J + U1##J) + U2##J;                                        \
    V##J.x = red32(s_.x) * (1.0f / 72.0f);                                   \
    V##J.y = red32(s_.y) * (1.0f / 72.0f); }

#define UPDJ(J)                                                              \
  { v2f pv_ = e0v * U0##J;                                                   \
    pv_ = pkfma(e1v, U1##J, pv_); pv_ = pkfma(e2v, U2##J, pv_);              \
    V##J.x = red32(pv_.x) * rs;                                              \
    V##J.y = red32(pv_.y) * rs; }

// ---- main kernel v14: 4096 blocks x 512 thr, 4 px, 2 waves/pixel ph2 ----
__global__ __launch_bounds__(512, 8)
void capsule_v14(const i4* __restrict__ xpi4, const i4* __restrict__ bfr,
                 float* __restrict__ out) {
    __shared__ float uLds[4 * 72 * STR];     // 38.25 KB -> 4 blocks/CU
    const int blk = blockIdx.x;              // 4096 = tt(8) x bb(2) x h(32) x wq(8)
    const int tt  = blk & 7;
    const int q   = blk >> 3;
    const int bb  = q >> 8;
    const int r   = q & 255;
    const int h   = r >> 3;
    const int w0  = (r & 7) << 2;
    const int tid = threadIdx.x;

    // ---- phase 1 (v13 verbatim): waves 0-3 compute, waves 4-7 wait ----
    {
        const int lane = tid & 63;
        const int wv   = tid >> 6;           // 0..7
        const int pl   = (lane & 31) >> 3;
        const int gl   = lane & 7;
        const int half = lane >> 5;
        const int tl   = lane & 31;
        const int wroff = tl + STR * 9 * 4 * half;

        if (wv < 4) {
            if (wv == 0) {
                i4 a0h, a0l, a1h, a1l, a2h, a2l;
                i4 b0h, b0l, b1h, b1l, b2h, b2l;
                bool ok0, ok1, ok2;
                ALOADIJ(a0h, a0l, ok0, 0) BLOADIJ(b0h, b0l, 0)
                ALOADIJ(a1h, a1l, ok1, 4) BLOADIJ(b1h, b1l, 4)
                PROCIJ(a0h, a0l, ok0, b0h, b0l, 0)
                ALOADIJ(a2h, a2l, ok2, 8) BLOADIJ(b2h, b2l, 8)
                PROCIJ(a1h, a1l, ok1, b1h, b1l, 4)
                PROCIJ(a2h, a2l, ok2, b2h, b2l, 8)
            } else if (wv == 1) {
                i4 a0h, a0l, a1h, a1l, b0h, b0l, b1h, b1l;
                bool ok0, ok1;
                ALOADIJ(a0h, a0l, ok0, 1) BLOADIJ(b0h, b0l, 1)
                ALOADIJ(a1h, a1l, ok1, 5) BLOADIJ(b1h, b1l, 5)
                PROCIJ(a0h, a0l, ok0, b0h, b0l, 1)
                PROCIJ(a1h, a1l, ok1, b1h, b1l, 5)
            } else if (wv == 2) {
                i4 a0h, a0l, a1h, a1l, b0h, b0l, b1h, b1l;
                bool ok0, ok1;
                ALOADIJ(a0h, a0l, ok0, 2) BLOADIJ(b0h, b0l, 2)
                ALOADIJ(a1h, a1l, ok1, 6) BLOADIJ(b1h, b1l, 6)
                PROCIJ(a0h, a0l, ok0, b0h, b0l, 2)
                PROCIJ(a1h, a1l, ok1, b1h, b1l, 6)
            } else {
                i4 a0h, a0l, a1h, a1l, b0h, b0l, b1h, b1l;
                bool ok0, ok1;
                ALOADIJ(a0h, a0l, ok0, 3) BLOADIJ(b0h, b0l, 3)
                ALOADIJ(a1h, a1l, ok1, 7) BLOADIJ(b1h, b1l, 7)
                PROCIJ(a0h, a0l, ok0, b0h, b0l, 3)
                PROCIJ(a1h, a1l, ok1, b1h, b1l, 7)
            }
        }
    }
    __syncthreads();

    // ---- phase 2: 8 waves = 4 pixels x 2 o-halves ----
    const int p  = tid >> 7;                 // pixel
    const int o2 = (tid >> 6) & 1;           // o-half (per wave)
    const int jh = (tid >> 5) & 1;           // l-half (lane bit 5)
    const int sc = tid & 31;                 // n-slice (lane bits 0-4)
    const bool has3 = (sc < 8);
    const float* rb = uLds + (p * 72 + sc) * STR + o2 * 16 + jh * 8;

    v2f U00, U01, U02, U03;                  // row sc
    v2f U10, U11, U12, U13;                  // row sc+32
    v2f U20, U21, U22, U23;                  // row sc+64 (sc<8)
    U20 = U21 = U22 = U23 = (v2f){0.0f, 0.0f};
    LROWV(U00, U01, U02, U03, 0)
    LROWV(U10, U11, U12, U13, 32)
    if (has3) LROWV(U20, U21, U22, U23, 64)

    v2f V0, V1, V2, V3;
    MEANJ(0) MEANJ(1) MEANJ(2) MEANJ(3)

    #pragma unroll 1
    for (int it = 0; it < 3; ++it) {
        v2f ssv = V0 * V0;
        ssv = pkfma(V1, V1, ssv); ssv = pkfma(V2, V2, ssv);
        ssv = pkfma(V3, V3, ssv);
        float ss = xor32_add(ssv.x + ssv.y);
        float inv = frcp(fmaxf(sqrtf(ss), 1e-12f));

        float E0 = __expf(DOTV(U00, U01, U02, U03) * inv);
        float E1 = __expf(DOTV(U10, U11, U12, U13) * inv);
        float E2 = has3 ? __expf(DOTV(U20, U21, U22, U23) * inv) : 0.0f;
        float ssum = red32((E0 + E1) + E2);
        float rs = frcp(ssum);

        v2f e0v = {E0, E0}, e1v = {E1, E1}, e2v = {E2, E2};
        UPDJ(0) UPDJ(1) UPDJ(2) UPDJ(3)
    }

    v2f ssv = V0 * V0;
    ssv = pkfma(V1, V1, ssv); ssv = pkfma(V2, V2, ssv);
    ssv = pkfma(V3, V3, ssv);
    float ss = xor32_add(ssv.x + ssv.y);
    float scale = sqrtf(ss) * frcp(1.0f + ss);

    v2f aa0 = (sc & 4) ? V2 : V0;
    v2f aa1 = (sc & 4) ? V3 : V1;
    v2f bb0 = (sc & 2) ? aa1 : aa0;
    float res = ((sc & 1) ? bb0.y : bb0.x) * scale;
    if (sc < 8) {
        int tg = tt * 32 + o2 * 16 + jh * 8 + sc;   // global channel
        out[((bb * 256 + tg) * 32 + h) * 32 + w0 + p] = res;
    }
}

// ---- fallback (tiny ws): self-contained (v9 verbatim) ----
__global__ __launch_bounds__(256, 1)
void capsule_fb(const float* __restrict__ x, const float* __restrict__ Wraw,
                float* __restrict__ out) {
    __shared__ float patch[9 * 128];
    const int blk = blockIdx.x;
    const int b = blk >> 10, h = (blk >> 5) & 31, w = blk & 31;
    const int t = threadIdx.x;

    const float* xb = x + b * (128 * 32 * 32);
    for (int idx = t; idx < 1152; idx += 256) {
        int c = idx / 9, ij = idx - c * 9;
        int di = ij / 3, dj = ij - di * 3;
        int hh = h + di - 1, ww = w + dj - 1;
        float v = 0.0f;
        if ((unsigned)hh < 32u && (unsigned)ww < 32u)
            v = xb[(c * 32 + hh) * 32 + ww];
        patch[ij * 128 + c] = v;
    }
    __syncthreads();

    float u[72];
    #pragma unroll
    for (int ij = 0; ij < 9; ++ij) {
        float wr[16];
        #pragma unroll
        for (int m = 0; m < 16; ++m) wr[m] = Wraw[(t * 16 + m) * 9 + ij];
        #pragma unroll
        for (int g = 0; g < 8; ++g) {
            float acc = 0.0f;
            #pragma unroll
            for (int m = 0; m < 16; ++m)
                acc = fmaf(patch[ij * 128 + g * 16 + m], wr[m], acc);
            u[g * 9 + ij] = acc;
        }
    }

    float v = 0.0f;
    #pragma unroll
    for (int n = 0; n < 72; ++n) v += u[n];
    v *= (1.0f / 72.0f);
    #pragma unroll 1
    for (int it = 0; it < 3; ++it) {
        float sg = dpp_add16(v * v);
        float vn = v * frcp(fmaxf(sqrtf(sg), 1e-12f));
        float ssum = 0.0f, vacc = 0.0f;
        #pragma unroll
        for (int n = 0; n < 72; ++n) {
            float pp = dpp_add16(u[n] * vn);
            float e = __expf(pp);
            ssum += e;
            vacc = fmaf(e, u[n], vacc);
        }
        v = vacc * frcp(ssum);
    }
    float sg = dpp_add16(v * v);
    float res = v * sqrtf(sg) * frcp(1.0f + sg);
    out[((b * 256 + t) * 32 + h) * 32 + w] = res;
}

extern "C" void kernel_launch(void* const* d_in, const int* in_sizes, int n_in,
                              void* d_out, int out_size, void* d_ws, size_t ws_size,
                              hipStream_t stream) {
    const float* x = (const float*)d_in[0];   // [2,128,32,32]
    const float* W = (const float*)d_in[1];   // [16,16,16,3,3]
    float* out = (float*)d_out;               // [2,256,32,32]
    i4* xP = (i4*)d_ws;                       // 1 MB
    unsigned short* Wbf = (unsigned short*)((char*)d_ws + 1048576);  // 144 KB

    const size_t need = 1048576 + (size_t)WBF_ELEMS * 2;
    if (ws_size >= need) {
        prep2_kernel<<<352, 256, 0, stream>>>(x, W, xP, Wbf);
        capsule_v14<<<4096, 512, 0, stream>>>(xP, (const i4*)Wbf, out);
    } else {
        capsule_fb<<<2048, 256, 0, stream>>>(x, W, out);
    }
}

// Round 8
// 90.262 us; speedup vs baseline: 1.0100x; 1.0100x over previous
//
#include <hip/hip_runtime.h>

// CapsuleConv2d, MI355X gfx950. ALL I/O FP32.
// B=2, C_in=128 (G=8 x M=16), 32x32, 3x3 pad 1, O=16, L=16 -> C_out=256.
// k-means (dot) routing 3 iters + squash.
//
// v15: v14's 2-waves/pixel phase-2 split was right (structure passed,
// occupancy doubled) but __launch_bounds__(512,8) + 80-live-VGPR phase 1
// spilled (VGPR_Count=32, VALUBusy 70% of spill traffic, dur flat 41us).
// v15 makes phase 1 FIT in the 64-VGPR budget instead of relaxing it:
//  - 9 ij tiles distributed over all 8 waves (wave wv -> ij=wv; wave 0
//    also ij=8), strict load->proc per ij: peak live ~45 VGPR.
//  - phase 2 v14-VERBATIM (passed, absmax identical): 2 waves/pixel,
//    red32 over sc, xor32 for jh-combine. 32 waves/CU -> 2x px throughput.
//  - prep2 (xP/Wbf pre-pack) and fallback unchanged.

typedef float v2f __attribute__((ext_vector_type(2)));
typedef int   i4  __attribute__((ext_vector_type(4)));
typedef short bh8 __attribute__((ext_vector_type(8)));
typedef float f16v __attribute__((ext_vector_type(16)));

#define STR 34                          // u LDS row stride (floats)
#define WBF_ELEMS 73728                 // Wbf u16 count (144 KB)

#define DPP_ADD(a, ctrl)                                                     \
  a += __int_as_float(__builtin_amdgcn_update_dpp(                           \
          0, __float_as_int(a), ctrl, 0xF, 0xF, true))

__device__ __forceinline__ float dpp_add16(float x) {
    float s = x;
    DPP_ADD(s, 0x128); DPP_ADD(s, 0x124); DPP_ADD(s, 0x122); DPP_ADD(s, 0x121);
    return s;
}

__device__ __forceinline__ float swz16_add(float x) {
    int y = __builtin_amdgcn_ds_swizzle(__float_as_int(x), 0x401F);
    return x + __int_as_float(y);
}

__device__ __forceinline__ float red32(float x) {
    return swz16_add(dpp_add16(x));
}

__device__ __forceinline__ float xor32_add(float x) {
    return x + __shfl_xor(x, 32, 64);
}

__device__ __forceinline__ float frcp(float x) {
    return __builtin_amdgcn_rcpf(x);
}

__device__ __forceinline__ v2f pkfma(v2f a, v2f b, v2f c) {
    return __builtin_elementwise_fma(a, b, c);
}

// ---- prep2 (v12/v13 verbatim): blk<64 -> xP pack; blk>=64 -> Wbf pack ----
__global__ __launch_bounds__(256)
void prep2_kernel(const float* __restrict__ x, const float* __restrict__ W,
                  i4* __restrict__ xP, unsigned short* __restrict__ Wbf) {
    const int blk = blockIdx.x;
    const int tid = threadIdx.x;
    if (blk < 64) {
        __shared__ float xs[128 * 33];
        const int b = blk >> 5, h = blk & 31;
        const float* xb = x + b * (128 * 32 * 32) + h * 32;
        #pragma unroll
        for (int k = 0; k < 16; ++k) {
            int idx = k * 256 + tid;
            int c = idx >> 5, w = idx & 31;
            xs[c * 33 + w] = xb[c * 1024 + w];
        }
        __syncthreads();
        i4* xo = xP + (b * 32 + h) * 1024;
        #pragma unroll
        for (int it = 0; it < 4; ++it) {
            int slot = it * 256 + tid;          // = w*32 + gl*4 + hf*2 + s
            int s  = slot & 1;
            int hf = (slot >> 1) & 1;
            int gl = (slot >> 2) & 7;
            int w  = slot >> 5;
            int c0 = gl * 16 + hf * 8;
            float f0 = xs[(c0 + 0) * 33 + w], f1 = xs[(c0 + 1) * 33 + w];
            float f2 = xs[(c0 + 2) * 33 + w], f3 = xs[(c0 + 3) * 33 + w];
            float f4 = xs[(c0 + 4) * 33 + w], f5 = xs[(c0 + 5) * 33 + w];
            float f6 = xs[(c0 + 6) * 33 + w], f7 = xs[(c0 + 7) * 33 + w];
            unsigned b0 = __float_as_uint(f0), b1 = __float_as_uint(f1);
            unsigned b2 = __float_as_uint(f2), b3 = __float_as_uint(f3);
            unsigned b4 = __float_as_uint(f4), b5 = __float_as_uint(f5);
            unsigned b6 = __float_as_uint(f6), b7 = __float_as_uint(f7);
            i4 pk;
            if (s == 0) {
                pk.x = (int)((b0 >> 16) | (b1 & 0xFFFF0000u));
                pk.y = (int)((b2 >> 16) | (b3 & 0xFFFF0000u));
                pk.z = (int)((b4 >> 16) | (b5 & 0xFFFF0000u));
                pk.w = (int)((b6 >> 16) | (b7 & 0xFFFF0000u));
            } else {
                unsigned l0 = __float_as_uint(f0 - __uint_as_float(b0 & 0xFFFF0000u));
                unsigned l1 = __float_as_uint(f1 - __uint_as_float(b1 & 0xFFFF0000u));
                unsigned l2 = __float_as_uint(f2 - __uint_as_float(b2 & 0xFFFF0000u));
                unsigned l3 = __float_as_uint(f3 - __uint_as_float(b3 & 0xFFFF0000u));
                unsigned l4 = __float_as_uint(f4 - __uint_as_float(b4 & 0xFFFF0000u));
                unsigned l5 = __float_as_uint(f5 - __uint_as_float(b5 & 0xFFFF0000u));
                unsigned l6 = __float_as_uint(f6 - __uint_as_float(b6 & 0xFFFF0000u));
                unsigned l7 = __float_as_uint(f7 - __uint_as_float(b7 & 0xFFFF0000u));
                pk.x = (int)((l0 >> 16) | (l1 & 0xFFFF0000u));
                pk.y = (int)((l2 >> 16) | (l3 & 0xFFFF0000u));
                pk.z = (int)((l4 >> 16) | (l5 & 0xFFFF0000u));
                pk.w = (int)((l6 >> 16) | (l7 & 0xFFFF0000u));
            }
            xo[slot] = pk;
        }
    } else {
        int idx = (blk - 64) * 256 + tid;     // 0..73727
        int j  = idx & 7;
        int L  = (idx >> 3) & 63;
        int s  = (idx >> 9) & 1;
        int tt = (idx >> 10) & 7;
        int ij = idx >> 13;
        int k  = (L >> 5) * 8 + j;
        int t  = tt * 32 + (L & 31);
        float wv = W[(t * 16 + k) * 9 + ij];
        unsigned bits = __float_as_uint(wv);
        unsigned hib  = bits & 0xFFFF0000u;
        unsigned short val;
        if (s == 0) val = (unsigned short)(hib >> 16);
        else {
            float lo = wv - __uint_as_float(hib);
            val = (unsigned short)(__float_as_uint(lo) >> 16);
        }
        Wbf[idx] = val;
    }
}

// ---- phase-1 macro: one ij = load A, load B, 3 MFMA, 16 CWR ----
// Strict per-ij scope keeps live state ~45 VGPR (fits 64-VGPR budget).
#define CWR(REG, IJ)                                                         \
    uLds[wroff + STR * ((((REG) >> 2) * 72) + (((REG) & 3) * 9) + (IJ))] =   \
        acc[(REG)];

#define ONEIJ(IJ) {                                                          \
    const int di = (IJ) / 3, dj = (IJ) % 3;                                  \
    const int hh = h + di - 1;                                               \
    const bool hok = (unsigned)hh < 32u;                                     \
    const int hhc = hok ? hh : 0;                                            \
    const int ww = w0 + pl + dj - 1;                                         \
    const bool ok = hok && ((unsigned)ww < 32u);                             \
    const int wwc = ok ? ww : 0;                                             \
    const int slot = (((bb * 32 + hhc) * 32 + wwc) * 8 + gl) * 2 + half;     \
    i4 ah = xpi4[slot * 2];                                                  \
    i4 al = xpi4[slot * 2 + 1];                                              \
    i4 bh = bfr[((IJ) * 8 + tt) * 128 + lane];                               \
    i4 bl = bfr[((IJ) * 8 + tt) * 128 + 64 + lane];                          \
    const i4 z_ = {0, 0, 0, 0};                                              \
    ah = ok ? ah : z_;                                                       \
    al = ok ? al : z_;                                                       \
    bh8 aHi = __builtin_bit_cast(bh8, ah);                                   \
    bh8 aLo = __builtin_bit_cast(bh8, al);                                   \
    bh8 bHi = __builtin_bit_cast(bh8, bh);                                   \
    bh8 bLo = __builtin_bit_cast(bh8, bl);                                   \
    f16v acc = {0.f,0.f,0.f,0.f,0.f,0.f,0.f,0.f,                             \
                0.f,0.f,0.f,0.f,0.f,0.f,0.f,0.f};                            \
    acc = __builtin_amdgcn_mfma_f32_32x32x16_bf16(aHi, bLo, acc, 0, 0, 0);   \
    acc = __builtin_amdgcn_mfma_f32_32x32x16_bf16(aLo, bHi, acc, 0, 0, 0);   \
    acc = __builtin_amdgcn_mfma_f32_32x32x16_bf16(aHi, bHi, acc, 0, 0, 0);   \
    CWR(0, IJ)  CWR(1, IJ)  CWR(2, IJ)  CWR(3, IJ)                           \
    CWR(4, IJ)  CWR(5, IJ)  CWR(6, IJ)  CWR(7, IJ)                           \
    CWR(8, IJ)  CWR(9, IJ)  CWR(10, IJ) CWR(11, IJ)                          \
    CWR(12, IJ) CWR(13, IJ) CWR(14, IJ) CWR(15, IJ) }

// ---- phase-2 macros (v14 verbatim) ----
#define LROWV(U0_, U1_, U2_, U3_, OFF)                                       \
  { const v2f* r2_ = (const v2f*)(rb + (OFF) * STR);                         \
    U0_ = r2_[0]; U1_ = r2_[1]; U2_ = r2_[2]; U3_ = r2_[3]; }

#define DOTV(UK0, UK1, UK2, UK3)                                             \
  ({ v2f d_ = UK0 * V0;                                                      \
     d_ = pkfma(UK1, V1, d_); d_ = pkfma(UK2, V2, d_);                       \
     d_ = pkfma(UK3, V3, d_); xor32_add(d_.x + d_.y); })

#define MEANJ(J)                                                             \
  { v2f s_ = (U0##J + U1##J) + U2##J;                                        \
    V##J.x = red32(s_.x) * (1.0f / 72.0f);                                   \
    V##J.y = red32(s_.y) * (1.0f / 72.0f); }

#define UPDJ(J)                                                              \
  { v2f pv_ = e0v * U0##J;                                                   \
    pv_ = pkfma(e1v, U1##J, pv_); pv_ = pkfma(e2v, U2##J, pv_);              \
    V##J.x = red32(pv_.x) * rs;                                              \
    V##J.y = red32(pv_.y) * rs; }

// ---- main kernel v15: 4096 x 512, 9 ij over 8 waves, 2 waves/px ph2 ----
__global__ __launch_bounds__(512, 8)
void capsule_v15(const i4* __restrict__ xpi4, const i4* __restrict__ bfr,
                 float* __restrict__ out) {
    __shared__ float uLds[4 * 72 * STR];     // 38.25 KB -> 4 blocks/CU
    const int blk = blockIdx.x;              // 4096 = tt(8) x bb(2) x h(32) x wq(8)
    const int tt  = blk & 7;
    const int q   = blk >> 3;
    const int bb  = q >> 8;
    const int r   = q & 255;
    const int h   = r >> 3;
    const int w0  = (r & 7) << 2;
    const int tid = threadIdx.x;

    // ---- phase 1: one ij per wave (wave 0 also ij=8), ~45 live VGPR ----
    {
        const int lane = tid & 63;
        const int wv   = tid >> 6;           // 0..7
        const int pl   = (lane & 31) >> 3;
        const int gl   = lane & 7;
        const int half = lane >> 5;
        const int tl   = lane & 31;
        const int wroff = tl + STR * 9 * 4 * half;

        if      (wv == 0) { ONEIJ(0) ONEIJ(8) }
        else if (wv == 1) { ONEIJ(1) }
        else if (wv == 2) { ONEIJ(2) }
        else if (wv == 3) { ONEIJ(3) }
        else if (wv == 4) { ONEIJ(4) }
        else if (wv == 5) { ONEIJ(5) }
        else if (wv == 6) { ONEIJ(6) }
        else              { ONEIJ(7) }
    }
    __syncthreads();

    // ---- phase 2 (v14 verbatim): 8 waves = 4 pixels x 2 o-halves ----
    const int p  = tid >> 7;                 // pixel
    const int o2 = (tid >> 6) & 1;           // o-half (per wave)
    const int jh = (tid >> 5) & 1;           // l-half (lane bit 5)
    const int sc = tid & 31;                 // n-slice (lane bits 0-4)
    const bool has3 = (sc < 8);
    const float* rb = uLds + (p * 72 + sc) * STR + o2 * 16 + jh * 8;

    v2f U00, U01, U02, U03;                  // row sc
    v2f U10, U11, U12, U13;                  // row sc+32
    v2f U20, U21, U22, U23;                  // row sc+64 (sc<8)
    U20 = U21 = U22 = U23 = (v2f){0.0f, 0.0f};
    LROWV(U00, U01, U02, U03, 0)
    LROWV(U10, U11, U12, U13, 32)
    if (has3) LROWV(U20, U21, U22, U23, 64)

    v2f V0, V1, V2, V3;
    MEANJ(0) MEANJ(1) MEANJ(2) MEANJ(3)

    #pragma unroll 1
    for (int it = 0; it < 3; ++it) {
        v2f ssv = V0 * V0;
        ssv = pkfma(V1, V1, ssv); ssv = pkfma(V2, V2, ssv);
        ssv = pkfma(V3, V3, ssv);
        float ss = xor32_add(ssv.x + ssv.y);
        float inv = frcp(fmaxf(sqrtf(ss), 1e-12f));

        float E0 = __expf(DOTV(U00, U01, U02, U03) * inv);
        float E1 = __expf(DOTV(U10, U11, U12, U13) * inv);
        float E2 = has3 ? __expf(DOTV(U20, U21, U22, U23) * inv) : 0.0f;
        float ssum = red32((E0 + E1) + E2);
        float rs = frcp(ssum);

        v2f e0v = {E0, E0}, e1v = {E1, E1}, e2v = {E2, E2};
        UPDJ(0) UPDJ(1) UPDJ(2) UPDJ(3)
    }

    v2f ssv = V0 * V0;
    ssv = pkfma(V1, V1, ssv); ssv = pkfma(V2, V2, ssv);
    ssv = pkfma(V3, V3, ssv);
    float ss = xor32_add(ssv.x + ssv.y);
    float scale = sqrtf(ss) * frcp(1.0f + ss);

    v2f aa0 = (sc & 4) ? V2 : V0;
    v2f aa1 = (sc & 4) ? V3 : V1;
    v2f bb0 = (sc & 2) ? aa1 : aa0;
    float res = ((sc & 1) ? bb0.y : bb0.x) * scale;
    if (sc < 8) {
        int tg = tt * 32 + o2 * 16 + jh * 8 + sc;   // global channel
        out[((bb * 256 + tg) * 32 + h) * 32 + w0 + p] = res;
    }
}

// ---- fallback (tiny ws): self-contained (v9 verbatim) ----
__global__ __launch_bounds__(256, 1)
void capsule_fb(const float* __restrict__ x, const float* __restrict__ Wraw,
                float* __restrict__ out) {
    __shared__ float patch[9 * 128];
    const int blk = blockIdx.x;
    const int b = blk >> 10, h = (blk >> 5) & 31, w = blk & 31;
    const int t = threadIdx.x;

    const float* xb = x + b * (128 * 32 * 32);
    for (int idx = t; idx < 1152; idx += 256) {
        int c = idx / 9, ij = idx - c * 9;
        int di = ij / 3, dj = ij - di * 3;
        int hh = h + di - 1, ww = w + dj - 1;
        float v = 0.0f;
        if ((unsigned)hh < 32u && (unsigned)ww < 32u)
            v = xb[(c * 32 + hh) * 32 + ww];
        patch[ij * 128 + c] = v;
    }
    __syncthreads();

    float u[72];
    #pragma unroll
    for (int ij = 0; ij < 9; ++ij) {
        float wr[16];
        #pragma unroll
        for (int m = 0; m < 16; ++m) wr[m] = Wraw[(t * 16 + m) * 9 + ij];
        #pragma unroll
        for (int g = 0; g < 8; ++g) {
            float acc = 0.0f;
            #pragma unroll
            for (int m = 0; m < 16; ++m)
                acc = fmaf(patch[ij * 128 + g * 16 + m], wr[m], acc);
            u[g * 9 + ij] = acc;
        }
    }

    float v = 0.0f;
    #pragma unroll
    for (int n = 0; n < 72; ++n) v += u[n];
    v *= (1.0f / 72.0f);
    #pragma unroll 1
    for (int it = 0; it < 3; ++it) {
        float sg = dpp_add16(v * v);
        float vn = v * frcp(fmaxf(sqrtf(sg), 1e-12f));
        float ssum = 0.0f, vacc = 0.0f;
        #pragma unroll
        for (int n = 0; n < 72; ++n) {
            float pp = dpp_add16(u[n] * vn);
            float e = __expf(pp);
            ssum += e;
            vacc = fmaf(e, u[n], vacc);
        }
        v = vacc * frcp(ssum);
    }
    float sg = dpp_add16(v * v);
    float res = v * sqrtf(sg) * frcp(1.0f + sg);
    out[((b * 256 + t) * 32 + h) * 32 + w] = res;
}

extern "C" void kernel_launch(void* const* d_in, const int* in_sizes, int n_in,
                              void* d_out, int out_size, void* d_ws, size_t ws_size,
                              hipStream_t stream) {
    const float* x = (const float*)d_in[0];   // [2,128,32,32]
    const float* W = (const float*)d_in[1];   // [16,16,16,3,3]
    float* out = (float*)d_out;               // [2,256,32,32]
    i4* xP = (i4*)d_ws;                       // 1 MB
    unsigned short* Wbf = (unsigned short*)((char*)d_ws + 1048576);  // 144 KB

    const size_t need = 1048576 + (size_t)WBF_ELEMS * 2;
    if (ws_size >= need) {
        prep2_kernel<<<352, 256, 0, stream>>>(x, W, xP, Wbf);
        capsule_v15<<<4096, 512, 0, stream>>>(xP, (const i4*)Wbf, out);
    } else {
        capsule_fb<<<2048, 256, 0, stream>>>(x, W, out);
    }
}

// Round 9
// 89.969 us; speedup vs baseline: 1.0133x; 1.0033x over previous
//
#include <hip/hip_runtime.h>

// CapsuleConv2d, MI355X gfx950. ALL I/O FP32.
// B=2, C_in=128 (G=8 x M=16), 32x32, 3x3 pad 1, O=16, L=16 -> C_out=256.
// k-means (dot) routing 3 iters + squash.
//
// v16 = v15 with __launch_bounds__(512, 4) ONLY (one-variable experiment).
// Evidence: (512,8) forces a 64-VGPR budget; allocator lands at 32 VGPR +
// spill traffic (v14 AND v15: VGPR_Count=32, VALUBusy ~70-74%, dur pinned
// at ~41us). v13 showed phase 2 is LATENCY-bound (VALU cuts were free), and
// v14/v15 proved the 2-waves-per-pixel split numerically (absmax identical).
// (512,4): 128-VGPR budget -> no spills; ~5 waves/SIMD -> 2 blocks/CU ->
// 16 waves/CU (same as v13) but HALF-length chains -> ~2x phase-2 rate if
// latency-bound. If it lands back at v13's ~29us capsule, phase 2 is
// issue-bound and the next lever is instruction count, not occupancy.
//  - phase 1: 9 ij over 8 waves (wave 0 does ij 0+8), ~45 live VGPR.
//  - phase 2: v14-verbatim 2-waves/pixel (red32 over sc, xor32 jh-combine).
//  - prep2 (xP/Wbf pre-pack) and fallback unchanged.

typedef float v2f __attribute__((ext_vector_type(2)));
typedef int   i4  __attribute__((ext_vector_type(4)));
typedef short bh8 __attribute__((ext_vector_type(8)));
typedef float f16v __attribute__((ext_vector_type(16)));

#define STR 34                          // u LDS row stride (floats)
#define WBF_ELEMS 73728                 // Wbf u16 count (144 KB)

#define DPP_ADD(a, ctrl)                                                     \
  a += __int_as_float(__builtin_amdgcn_update_dpp(                           \
          0, __float_as_int(a), ctrl, 0xF, 0xF, true))

__device__ __forceinline__ float dpp_add16(float x) {
    float s = x;
    DPP_ADD(s, 0x128); DPP_ADD(s, 0x124); DPP_ADD(s, 0x122); DPP_ADD(s, 0x121);
    return s;
}

__device__ __forceinline__ float swz16_add(float x) {
    int y = __builtin_amdgcn_ds_swizzle(__float_as_int(x), 0x401F);
    return x + __int_as_float(y);
}

__device__ __forceinline__ float red32(float x) {
    return swz16_add(dpp_add16(x));
}

__device__ __forceinline__ float xor32_add(float x) {
    return x + __shfl_xor(x, 32, 64);
}

__device__ __forceinline__ float frcp(float x) {
    return __builtin_amdgcn_rcpf(x);
}

__device__ __forceinline__ v2f pkfma(v2f a, v2f b, v2f c) {
    return __builtin_elementwise_fma(a, b, c);
}

// ---- prep2 (v12/v13 verbatim): blk<64 -> xP pack; blk>=64 -> Wbf pack ----
__global__ __launch_bounds__(256)
void prep2_kernel(const float* __restrict__ x, const float* __restrict__ W,
                  i4* __restrict__ xP, unsigned short* __restrict__ Wbf) {
    const int blk = blockIdx.x;
    const int tid = threadIdx.x;
    if (blk < 64) {
        __shared__ float xs[128 * 33];
        const int b = blk >> 5, h = blk & 31;
        const float* xb = x + b * (128 * 32 * 32) + h * 32;
        #pragma unroll
        for (int k = 0; k < 16; ++k) {
            int idx = k * 256 + tid;
            int c = idx >> 5, w = idx & 31;
            xs[c * 33 + w] = xb[c * 1024 + w];
        }
        __syncthreads();
        i4* xo = xP + (b * 32 + h) * 1024;
        #pragma unroll
        for (int it = 0; it < 4; ++it) {
            int slot = it * 256 + tid;          // = w*32 + gl*4 + hf*2 + s
            int s  = slot & 1;
            int hf = (slot >> 1) & 1;
            int gl = (slot >> 2) & 7;
            int w  = slot >> 5;
            int c0 = gl * 16 + hf * 8;
            float f0 = xs[(c0 + 0) * 33 + w], f1 = xs[(c0 + 1) * 33 + w];
            float f2 = xs[(c0 + 2) * 33 + w], f3 = xs[(c0 + 3) * 33 + w];
            float f4 = xs[(c0 + 4) * 33 + w], f5 = xs[(c0 + 5) * 33 + w];
            float f6 = xs[(c0 + 6) * 33 + w], f7 = xs[(c0 + 7) * 33 + w];
            unsigned b0 = __float_as_uint(f0), b1 = __float_as_uint(f1);
            unsigned b2 = __float_as_uint(f2), b3 = __float_as_uint(f3);
            unsigned b4 = __float_as_uint(f4), b5 = __float_as_uint(f5);
            unsigned b6 = __float_as_uint(f6), b7 = __float_as_uint(f7);
            i4 pk;
            if (s == 0) {
                pk.x = (int)((b0 >> 16) | (b1 & 0xFFFF0000u));
                pk.y = (int)((b2 >> 16) | (b3 & 0xFFFF0000u));
                pk.z = (int)((b4 >> 16) | (b5 & 0xFFFF0000u));
                pk.w = (int)((b6 >> 16) | (b7 & 0xFFFF0000u));
            } else {
                unsigned l0 = __float_as_uint(f0 - __uint_as_float(b0 & 0xFFFF0000u));
                unsigned l1 = __float_as_uint(f1 - __uint_as_float(b1 & 0xFFFF0000u));
                unsigned l2 = __float_as_uint(f2 - __uint_as_float(b2 & 0xFFFF0000u));
                unsigned l3 = __float_as_uint(f3 - __uint_as_float(b3 & 0xFFFF0000u));
                unsigned l4 = __float_as_uint(f4 - __uint_as_float(b4 & 0xFFFF0000u));
                unsigned l5 = __float_as_uint(f5 - __uint_as_float(b5 & 0xFFFF0000u));
                unsigned l6 = __float_as_uint(f6 - __uint_as_float(b6 & 0xFFFF0000u));
                unsigned l7 = __float_as_uint(f7 - __uint_as_float(b7 & 0xFFFF0000u));
                pk.x = (int)((l0 >> 16) | (l1 & 0xFFFF0000u));
                pk.y = (int)((l2 >> 16) | (l3 & 0xFFFF0000u));
                pk.z = (int)((l4 >> 16) | (l5 & 0xFFFF0000u));
                pk.w = (int)((l6 >> 16) | (l7 & 0xFFFF0000u));
            }
            xo[slot] = pk;
        }
    } else {
        int idx = (blk - 64) * 256 + tid;     // 0..73727
        int j  = idx & 7;
        int L  = (idx >> 3) & 63;
        int s  = (idx >> 9) & 1;
        int tt = (idx >> 10) & 7;
        int ij = idx >> 13;
        int k  = (L >> 5) * 8 + j;
        int t  = tt * 32 + (L & 31);
        float wv = W[(t * 16 + k) * 9 + ij];
        unsigned bits = __float_as_uint(wv);
        unsigned hib  = bits & 0xFFFF0000u;
        unsigned short val;
        if (s == 0) val = (unsigned short)(hib >> 16);
        else {
            float lo = wv - __uint_as_float(hib);
            val = (unsigned short)(__float_as_uint(lo) >> 16);
        }
        Wbf[idx] = val;
    }
}

// ---- phase-1 macro: one ij = load A, load B, 3 MFMA, 16 CWR ----
#define CWR(REG, IJ)                                                         \
    uLds[wroff + STR * ((((REG) >> 2) * 72) + (((REG) & 3) * 9) + (IJ))] =   \
        acc[(REG)];

#define ONEIJ(IJ) {                                                          \
    const int di = (IJ) / 3, dj = (IJ) % 3;                                  \
    const int hh = h + di - 1;                                               \
    const bool hok = (unsigned)hh < 32u;                                     \
    const int hhc = hok ? hh : 0;                                            \
    const int ww = w0 + pl + dj - 1;                                         \
    const bool ok = hok && ((unsigned)ww < 32u);                             \
    const int wwc = ok ? ww : 0;                                             \
    const int slot = (((bb * 32 + hhc) * 32 + wwc) * 8 + gl) * 2 + half;     \
    i4 ah = xpi4[slot * 2];                                                  \
    i4 al = xpi4[slot * 2 + 1];                                              \
    i4 bh = bfr[((IJ) * 8 + tt) * 128 + lane];                               \
    i4 bl = bfr[((IJ) * 8 + tt) * 128 + 64 + lane];                          \
    const i4 z_ = {0, 0, 0, 0};                                              \
    ah = ok ? ah : z_;                                                       \
    al = ok ? al : z_;                                                       \
    bh8 aHi = __builtin_bit_cast(bh8, ah);                                   \
    bh8 aLo = __builtin_bit_cast(bh8, al);                                   \
    bh8 bHi = __builtin_bit_cast(bh8, bh);                                   \
    bh8 bLo = __builtin_bit_cast(bh8, bl);                                   \
    f16v acc = {0.f,0.f,0.f,0.f,0.f,0.f,0.f,0.f,                             \
                0.f,0.f,0.f,0.f,0.f,0.f,0.f,0.f};                            \
    acc = __builtin_amdgcn_mfma_f32_32x32x16_bf16(aHi, bLo, acc, 0, 0, 0);   \
    acc = __builtin_amdgcn_mfma_f32_32x32x16_bf16(aLo, bHi, acc, 0, 0, 0);   \
    acc = __builtin_amdgcn_mfma_f32_32x32x16_bf16(aHi, bHi, acc, 0, 0, 0);   \
    CWR(0, IJ)  CWR(1, IJ)  CWR(2, IJ)  CWR(3, IJ)                           \
    CWR(4, IJ)  CWR(5, IJ)  CWR(6, IJ)  CWR(7, IJ)                           \
    CWR(8, IJ)  CWR(9, IJ)  CWR(10, IJ) CWR(11, IJ)                          \
    CWR(12, IJ) CWR(13, IJ) CWR(14, IJ) CWR(15, IJ) }

// ---- phase-2 macros (v14 verbatim) ----
#define LROWV(U0_, U1_, U2_, U3_, OFF)                                       \
  { const v2f* r2_ = (const v2f*)(rb + (OFF) * STR);                         \
    U0_ = r2_[0]; U1_ = r2_[1]; U2_ = r2_[2]; U3_ = r2_[3]; }

#define DOTV(UK0, UK1, UK2, UK3)                                             \
  ({ v2f d_ = UK0 * V0;                                                      \
     d_ = pkfma(UK1, V1, d_); d_ = pkfma(UK2, V2, d_);                       \
     d_ = pkfma(UK3, V3, d_); xor32_add(d_.x + d_.y); })

#define MEANJ(J)                                                             \
  { v2f s_ = (U0##J + U1##J) + U2##J;                                        \
    V##J.x = red32(s_.x) * (1.0f / 72.0f);                                   \
    V##J.y = red32(s_.y) * (1.0f / 72.0f); }

#define UPDJ(J)                                                              \
  { v2f pv_ = e0v * U0##J;                                                   \
    pv_ = pkfma(e1v, U1##J, pv_); pv_ = pkfma(e2v, U2##J, pv_);              \
    V##J.x = red32(pv_.x) * rs;                                              \
    V##J.y = red32(pv_.y) * rs; }

// ---- main kernel v16: 4096 x 512, (512,4) -> no spills, 2 waves/px ph2 ----
__global__ __launch_bounds__(512, 4)
void capsule_v16(const i4* __restrict__ xpi4, const i4* __restrict__ bfr,
                 float* __restrict__ out) {
    __shared__ float uLds[4 * 72 * STR];     // 38.25 KB
    const int blk = blockIdx.x;              // 4096 = tt(8) x bb(2) x h(32) x wq(8)
    const int tt  = blk & 7;
    const int q   = blk >> 3;
    const int bb  = q >> 8;
    const int r   = q & 255;
    const int h   = r >> 3;
    const int w0  = (r & 7) << 2;
    const int tid = threadIdx.x;

    // ---- phase 1: one ij per wave (wave 0 also ij=8), ~45 live VGPR ----
    {
        const int lane = tid & 63;
        const int wv   = tid >> 6;           // 0..7
        const int pl   = (lane & 31) >> 3;
        const int gl   = lane & 7;
        const int half = lane >> 5;
        const int tl   = lane & 31;
        const int wroff = tl + STR * 9 * 4 * half;

        if      (wv == 0) { ONEIJ(0) ONEIJ(8) }
        else if (wv == 1) { ONEIJ(1) }
        else if (wv == 2) { ONEIJ(2) }
        else if (wv == 3) { ONEIJ(3) }
        else if (wv == 4) { ONEIJ(4) }
        else if (wv == 5) { ONEIJ(5) }
        else if (wv == 6) { ONEIJ(6) }
        else              { ONEIJ(7) }
    }
    __syncthreads();

    // ---- phase 2 (v14 verbatim): 8 waves = 4 pixels x 2 o-halves ----
    const int p  = tid >> 7;                 // pixel
    const int o2 = (tid >> 6) & 1;           // o-half (per wave)
    const int jh = (tid >> 5) & 1;           // l-half (lane bit 5)
    const int sc = tid & 31;                 // n-slice (lane bits 0-4)
    const bool has3 = (sc < 8);
    const float* rb = uLds + (p * 72 + sc) * STR + o2 * 16 + jh * 8;

    v2f U00, U01, U02, U03;                  // row sc
    v2f U10, U11, U12, U13;                  // row sc+32
    v2f U20, U21, U22, U23;                  // row sc+64 (sc<8)
    U20 = U21 = U22 = U23 = (v2f){0.0f, 0.0f};
    LROWV(U00, U01, U02, U03, 0)
    LROWV(U10, U11, U12, U13, 32)
    if (has3) LROWV(U20, U21, U22, U23, 64)

    v2f V0, V1, V2, V3;
    MEANJ(0) MEANJ(1) MEANJ(2) MEANJ(3)

    #pragma unroll 1
    for (int it = 0; it < 3; ++it) {
        v2f ssv = V0 * V0;
        ssv = pkfma(V1, V1, ssv); ssv = pkfma(V2, V2, ssv);
        ssv = pkfma(V3, V3, ssv);
        float ss = xor32_add(ssv.x + ssv.y);
        float inv = frcp(fmaxf(sqrtf(ss), 1e-12f));

        float E0 = __expf(DOTV(U00, U01, U02, U03) * inv);
        float E1 = __expf(DOTV(U10, U11, U12, U13) * inv);
        float E2 = has3 ? __expf(DOTV(U20, U21, U22, U23) * inv) : 0.0f;
        float ssum = red32((E0 + E1) + E2);
        float rs = frcp(ssum);

        v2f e0v = {E0, E0}, e1v = {E1, E1}, e2v = {E2, E2};
        UPDJ(0) UPDJ(1) UPDJ(2) UPDJ(3)
    }

    v2f ssv = V0 * V0;
    ssv = pkfma(V1, V1, ssv); ssv = pkfma(V2, V2, ssv);
    ssv = pkfma(V3, V3, ssv);
    float ss = xor32_add(ssv.x + ssv.y);
    float scale = sqrtf(ss) * frcp(1.0f + ss);

    v2f aa0 = (sc & 4) ? V2 : V0;
    v2f aa1 = (sc & 4) ? V3 : V1;
    v2f bb0 = (sc & 2) ? aa1 : aa0;
    float res = ((sc & 1) ? bb0.y : bb0.x) * scale;
    if (sc < 8) {
        int tg = tt * 32 + o2 * 16 + jh * 8 + sc;   // global channel
        out[((bb * 256 + tg) * 32 + h) * 32 + w0 + p] = res;
    }
}

// ---- fallback (tiny ws): self-contained (v9 verbatim) ----
__global__ __launch_bounds__(256, 1)
void capsule_fb(const float* __restrict__ x, const float* __restrict__ Wraw,
                float* __restrict__ out) {
    __shared__ float patch[9 * 128];
    const int blk = blockIdx.x;
    const int b = blk >> 10, h = (blk >> 5) & 31, w = blk & 31;
    const int t = threadIdx.x;

    const float* xb = x + b * (128 * 32 * 32);
    for (int idx = t; idx < 1152; idx += 256) {
        int c = idx / 9, ij = idx - c * 9;
        int di = ij / 3, dj = ij - di * 3;
        int hh = h + di - 1, ww = w + dj - 1;
        float v = 0.0f;
        if ((unsigned)hh < 32u && (unsigned)ww < 32u)
            v = xb[(c * 32 + hh) * 32 + ww];
        patch[ij * 128 + c] = v;
    }
    __syncthreads();

    float u[72];
    #pragma unroll
    for (int ij = 0; ij < 9; ++ij) {
        float wr[16];
        #pragma unroll
        for (int m = 0; m < 16; ++m) wr[m] = Wraw[(t * 16 + m) * 9 + ij];
        #pragma unroll
        for (int g = 0; g < 8; ++g) {
            float acc = 0.0f;
            #pragma unroll
            for (int m = 0; m < 16; ++m)
                acc = fmaf(patch[ij * 128 + g * 16 + m], wr[m], acc);
            u[g * 9 + ij] = acc;
        }
    }

    float v = 0.0f;
    #pragma unroll
    for (int n = 0; n < 72; ++n) v += u[n];
    v *= (1.0f / 72.0f);
    #pragma unroll 1
    for (int it = 0; it < 3; ++it) {
        float sg = dpp_add16(v * v);
        float vn = v * frcp(fmaxf(sqrtf(sg), 1e-12f));
        float ssum = 0.0f, vacc = 0.0f;
        #pragma unroll
        for (int n = 0; n < 72; ++n) {
            float pp = dpp_add16(u[n] * vn);
            float e = __expf(pp);
            ssum += e;
            vacc = fmaf(e, u[n], vacc);
        }
        v = vacc * frcp(ssum);
    }
    float sg = dpp_add16(v * v);
    float res = v * sqrtf(sg) * frcp(1.0f + sg);
    out[((b * 256 + t) * 32 + h) * 32 + w] = res;
}

extern "C" void kernel_launch(void* const* d_in, const int* in_sizes, int n_in,
                              void* d_out, int out_size, void* d_ws, size_t ws_size,
                              hipStream_t stream) {
    const float* x = (const float*)d_in[0];   // [2,128,32,32]
    const float* W = (const float*)d_in[1];   // [16,16,16,3,3]
    float* out = (float*)d_out;               // [2,256,32,32]
    i4* xP = (i4*)d_ws;                       // 1 MB
    unsigned short* Wbf = (unsigned short*)((char*)d_ws + 1048576);  // 144 KB

    const size_t need = 1048576 + (size_t)WBF_ELEMS * 2;
    if (ws_size >= need) {
        prep2_kernel<<<352, 256, 0, stream>>>(x, W, xP, Wbf);
        capsule_v16<<<4096, 512, 0, stream>>>(xP, (const i4*)Wbf, out);
    } else {
        capsule_fb<<<2048, 256, 0, stream>>>(x, W, out);
    }
}

// Round 10
// 83.079 us; speedup vs baseline: 1.0973x; 1.0829x over previous
//
#include <hip/hip_runtime.h>

// CapsuleConv2d, MI355X gfx950. ALL I/O FP32.
// B=2, C_in=128 (G=8 x M=16), 32x32, 3x3 pad 1, O=16, L=16 -> C_out=256.
// k-means (dot) routing 3 iters + squash.
//
// v17: break the 16-chains/CU wall. Evidence chain:
//  - chains/CU = resident pixels = 160KB / 9.8KB(f32 u) = 16 for EVERY f32
//    structure (v9..v16). 27us capsule is pinned by this.
//  - 8 waves/EU needs <=64 VGPR (m69 tier); compiler auto-targets the tier
//    LDS allows -> 512-thr variants junk-compiled (VGPR=32, +spill VALU).
//  - Unique fix: fp16 u (19.58KB -> 8 blocks/CU) + 128-thr blocks (2 waves;
//    LDS caps occupancy at 16 waves/CU = 4 waves/EU -> compiler targets the
//    128-VGPR tier, no junk) + ILP-2 phase 2 (each wave routes 2 pixels,
//    interleaved chains) -> 32 chains/CU, 2 residency rounds (was 4).
//  - Routing math stays f32 in v13's exact op order; only u is fp16 (RTNE).
//    absmax may grow ~4.9e-4 -> ~7e-4 (u rel eps 2^-11; errors average in
//    the softmax-weighted mean). If checker rejects, revert to v13.

typedef float v2f __attribute__((ext_vector_type(2)));
typedef int   i4  __attribute__((ext_vector_type(4)));
typedef short bh8 __attribute__((ext_vector_type(8)));
typedef float f16v __attribute__((ext_vector_type(16)));
typedef _Float16 h2v __attribute__((ext_vector_type(2)));

#define STRH 34                         // u LDS row stride (halves)
#define WBF_ELEMS 73728                 // Wbf u16 count (144 KB)

#define DPP_ADD(a, ctrl)                                                     \
  a += __int_as_float(__builtin_amdgcn_update_dpp(                           \
          0, __float_as_int(a), ctrl, 0xF, 0xF, true))

__device__ __forceinline__ float dpp_add16(float x) {
    float s = x;
    DPP_ADD(s, 0x128); DPP_ADD(s, 0x124); DPP_ADD(s, 0x122); DPP_ADD(s, 0x121);
    return s;
}

__device__ __forceinline__ float swz16_add(float x) {
    int y = __builtin_amdgcn_ds_swizzle(__float_as_int(x), 0x401F);
    return x + __int_as_float(y);
}

__device__ __forceinline__ float frcp(float x) {
    return __builtin_amdgcn_rcpf(x);
}

__device__ __forceinline__ v2f pkfma(v2f a, v2f b, v2f c) {
    return __builtin_elementwise_fma(a, b, c);
}

__device__ __forceinline__ v2f i2f(int u) {
    h2v h = __builtin_bit_cast(h2v, u);
    return (v2f){(float)h.x, (float)h.y};
}

// ---- prep2 (v12/v13 verbatim): blk<64 -> xP pack; blk>=64 -> Wbf pack ----
__global__ __launch_bounds__(256)
void prep2_kernel(const float* __restrict__ x, const float* __restrict__ W,
                  i4* __restrict__ xP, unsigned short* __restrict__ Wbf) {
    const int blk = blockIdx.x;
    const int tid = threadIdx.x;
    if (blk < 64) {
        __shared__ float xs[128 * 33];
        const int b = blk >> 5, h = blk & 31;
        const float* xb = x + b * (128 * 32 * 32) + h * 32;
        #pragma unroll
        for (int k = 0; k < 16; ++k) {
            int idx = k * 256 + tid;
            int c = idx >> 5, w = idx & 31;
            xs[c * 33 + w] = xb[c * 1024 + w];
        }
        __syncthreads();
        i4* xo = xP + (b * 32 + h) * 1024;
        #pragma unroll
        for (int it = 0; it < 4; ++it) {
            int slot = it * 256 + tid;          // = w*32 + gl*4 + hf*2 + s
            int s  = slot & 1;
            int hf = (slot >> 1) & 1;
            int gl = (slot >> 2) & 7;
            int w  = slot >> 5;
            int c0 = gl * 16 + hf * 8;
            float f0 = xs[(c0 + 0) * 33 + w], f1 = xs[(c0 + 1) * 33 + w];
            float f2 = xs[(c0 + 2) * 33 + w], f3 = xs[(c0 + 3) * 33 + w];
            float f4 = xs[(c0 + 4) * 33 + w], f5 = xs[(c0 + 5) * 33 + w];
            float f6 = xs[(c0 + 6) * 33 + w], f7 = xs[(c0 + 7) * 33 + w];
            unsigned b0 = __float_as_uint(f0), b1 = __float_as_uint(f1);
            unsigned b2 = __float_as_uint(f2), b3 = __float_as_uint(f3);
            unsigned b4 = __float_as_uint(f4), b5 = __float_as_uint(f5);
            unsigned b6 = __float_as_uint(f6), b7 = __float_as_uint(f7);
            i4 pk;
            if (s == 0) {
                pk.x = (int)((b0 >> 16) | (b1 & 0xFFFF0000u));
                pk.y = (int)((b2 >> 16) | (b3 & 0xFFFF0000u));
                pk.z = (int)((b4 >> 16) | (b5 & 0xFFFF0000u));
                pk.w = (int)((b6 >> 16) | (b7 & 0xFFFF0000u));
            } else {
                unsigned l0 = __float_as_uint(f0 - __uint_as_float(b0 & 0xFFFF0000u));
                unsigned l1 = __float_as_uint(f1 - __uint_as_float(b1 & 0xFFFF0000u));
                unsigned l2 = __float_as_uint(f2 - __uint_as_float(b2 & 0xFFFF0000u));
                unsigned l3 = __float_as_uint(f3 - __uint_as_float(b3 & 0xFFFF0000u));
                unsigned l4 = __float_as_uint(f4 - __uint_as_float(b4 & 0xFFFF0000u));
                unsigned l5 = __float_as_uint(f5 - __uint_as_float(b5 & 0xFFFF0000u));
                unsigned l6 = __float_as_uint(f6 - __uint_as_float(b6 & 0xFFFF0000u));
                unsigned l7 = __float_as_uint(f7 - __uint_as_float(b7 & 0xFFFF0000u));
                pk.x = (int)((l0 >> 16) | (l1 & 0xFFFF0000u));
                pk.y = (int)((l2 >> 16) | (l3 & 0xFFFF0000u));
                pk.z = (int)((l4 >> 16) | (l5 & 0xFFFF0000u));
                pk.w = (int)((l6 >> 16) | (l7 & 0xFFFF0000u));
            }
            xo[slot] = pk;
        }
    } else {
        int idx = (blk - 64) * 256 + tid;     // 0..73727
        int j  = idx & 7;
        int L  = (idx >> 3) & 63;
        int s  = (idx >> 9) & 1;
        int tt = (idx >> 10) & 7;
        int ij = idx >> 13;
        int k  = (L >> 5) * 8 + j;
        int t  = tt * 32 + (L & 31);
        float wv = W[(t * 16 + k) * 9 + ij];
        unsigned bits = __float_as_uint(wv);
        unsigned hib  = bits & 0xFFFF0000u;
        unsigned short val;
        if (s == 0) val = (unsigned short)(hib >> 16);
        else {
            float lo = wv - __uint_as_float(hib);
            val = (unsigned short)(__float_as_uint(lo) >> 16);
        }
        Wbf[idx] = val;
    }
}

// ---- phase-1 macro: one ij = load A, load B, 3 MFMA, 16 cvt+CWR(fp16) ----
#define CWRH(REG, IJ)                                                        \
    uH[wroff + STRH * ((((REG) >> 2) * 72) + (((REG) & 3) * 9) + (IJ))] =    \
        (_Float16)acc[(REG)];

#define ONEIJ(IJ) {                                                          \
    const int di = (IJ) / 3, dj = (IJ) % 3;                                  \
    const int hh = h + di - 1;                                               \
    const bool hok = (unsigned)hh < 32u;                                     \
    const int hhc = hok ? hh : 0;                                            \
    const int ww = w0 + pl + dj - 1;                                         \
    const bool ok = hok && ((unsigned)ww < 32u);                             \
    const int wwc = ok ? ww : 0;                                             \
    const int slot = (((bb * 32 + hhc) * 32 + wwc) * 8 + gl) * 2 + half;     \
    i4 ah = xpi4[slot * 2];                                                  \
    i4 al = xpi4[slot * 2 + 1];                                              \
    i4 bh = bfr[((IJ) * 8 + tt) * 128 + lane];                               \
    i4 bl = bfr[((IJ) * 8 + tt) * 128 + 64 + lane];                          \
    const i4 z_ = {0, 0, 0, 0};                                              \
    ah = ok ? ah : z_;                                                       \
    al = ok ? al : z_;                                                       \
    bh8 aHi = __builtin_bit_cast(bh8, ah);                                   \
    bh8 aLo = __builtin_bit_cast(bh8, al);                                   \
    bh8 bHi = __builtin_bit_cast(bh8, bh);                                   \
    bh8 bLo = __builtin_bit_cast(bh8, bl);                                   \
    f16v acc = {0.f,0.f,0.f,0.f,0.f,0.f,0.f,0.f,                             \
                0.f,0.f,0.f,0.f,0.f,0.f,0.f,0.f};                            \
    acc = __builtin_amdgcn_mfma_f32_32x32x16_bf16(aHi, bLo, acc, 0, 0, 0);   \
    acc = __builtin_amdgcn_mfma_f32_32x32x16_bf16(aLo, bHi, acc, 0, 0, 0);   \
    acc = __builtin_amdgcn_mfma_f32_32x32x16_bf16(aHi, bHi, acc, 0, 0, 0);   \
    CWRH(0, IJ)  CWRH(1, IJ)  CWRH(2, IJ)  CWRH(3, IJ)                       \
    CWRH(4, IJ)  CWRH(5, IJ)  CWRH(6, IJ)  CWRH(7, IJ)                       \
    CWRH(8, IJ)  CWRH(9, IJ)  CWRH(10, IJ) CWRH(11, IJ)                      \
    CWRH(12, IJ) CWRH(13, IJ) CWRH(14, IJ) CWRH(15, IJ) }

// ---- phase-2 macros: packed-fp16 U rows, f32 math, v13 op order ----
#define LROWP(P, K) {                                                        \
    const int* r_ = (const int*)(rb##P + (K) * 16 * STRH);                   \
    U##K##P.x = r_[0]; U##K##P.y = r_[1]; U##K##P.z = r_[2]; U##K##P.w = r_[3]; }

#define DOTP(P, K)                                                           \
  ({ v2f d_ = i2f(U##K##P.x) * V0##P;                                        \
     d_ = pkfma(i2f(U##K##P.y), V1##P, d_);                                  \
     d_ = pkfma(i2f(U##K##P.z), V2##P, d_);                                  \
     d_ = pkfma(i2f(U##K##P.w), V3##P, d_);                                  \
     swz16_add(d_.x + d_.y); })

#define MEANC(P, C, J) {                                                     \
    v2f s_ = (i2f(U0##P.C) + i2f(U1##P.C)) + (i2f(U2##P.C) + i2f(U3##P.C))   \
             + i2f(U4##P.C);                                                 \
    V##J##P.x = dpp_add16(s_.x) * (1.0f / 72.0f);                            \
    V##J##P.y = dpp_add16(s_.y) * (1.0f / 72.0f); }

#define UPDC(P, C, J) {                                                      \
    v2f pv_ = e0##P * i2f(U0##P.C);                                          \
    pv_ = pkfma(e1##P, i2f(U1##P.C), pv_);                                   \
    pv_ = pkfma(e2##P, i2f(U2##P.C), pv_);                                   \
    pv_ = pkfma(e3##P, i2f(U3##P.C), pv_);                                   \
    pv_ = pkfma(e4##P, i2f(U4##P.C), pv_);                                   \
    V##J##P.x = dpp_add16(pv_.x) * rs##P;                                    \
    V##J##P.y = dpp_add16(pv_.y) * rs##P; }

// ---- main kernel v17: 4096 x 128 thr, fp16 u, 8 blk/CU, ILP-2 phase 2 ----
__global__ __launch_bounds__(128, 4)
void capsule_v17(const i4* __restrict__ xpi4, const i4* __restrict__ bfr,
                 float* __restrict__ out) {
    __shared__ _Float16 uH[4 * 72 * STRH];   // 19.58 KB -> 8 blocks/CU
    const int blk = blockIdx.x;              // 4096 = tt(8) x bb(2) x h(32) x wq(8)
    const int tt  = blk & 7;
    const int q   = blk >> 3;
    const int bb  = q >> 8;
    const int r   = q & 255;
    const int h   = r >> 3;
    const int w0  = (r & 7) << 2;
    const int tid = threadIdx.x;             // 0..127 (2 waves)
    const int lane = tid & 63;
    const int wv   = tid >> 6;               // 0..1

    // ---- phase 1: 9 ij over 2 waves (wv0: 0,2,4,6,8 / wv1: 1,3,5,7) ----
    {
        const int pl   = (lane & 31) >> 3;
        const int gl   = lane & 7;
        const int half = lane >> 5;
        const int tl   = lane & 31;
        const int wroff = tl + STRH * 9 * 4 * half;

        if (wv == 0) { ONEIJ(0) ONEIJ(2) ONEIJ(4) ONEIJ(6) ONEIJ(8) }
        else         { ONEIJ(1) ONEIJ(3) ONEIJ(5) ONEIJ(7) }
    }
    __syncthreads();

    // ---- phase 2: wave wv routes pixels {2wv, 2wv+1} via ILP-2 ----
    const int pA = 2 * wv, pB = 2 * wv + 1;
    const int i6 = lane;
    const int o2 = i6 >> 5;
    const int jh = (i6 >> 4) & 1;
    const int sc = i6 & 15;
    const bool has5 = (sc < 8);
    const _Float16* rbA = uH + (pA * 72 + sc) * STRH + o2 * 16 + jh * 8;
    const _Float16* rbB = uH + (pB * 72 + sc) * STRH + o2 * 16 + jh * 8;

    i4 U0A, U1A, U2A, U3A, U4A;              // rows sc+16K, packed fp16
    i4 U0B, U1B, U2B, U3B, U4B;
    U4A = (i4){0,0,0,0}; U4B = (i4){0,0,0,0};
    LROWP(A, 0) LROWP(B, 0)
    LROWP(A, 1) LROWP(B, 1)
    LROWP(A, 2) LROWP(B, 2)
    LROWP(A, 3) LROWP(B, 3)
    if (has5) { LROWP(A, 4) LROWP(B, 4) }

    v2f V0A, V1A, V2A, V3A;
    v2f V0B, V1B, V2B, V3B;
    MEANC(A, x, 0) MEANC(A, y, 1) MEANC(A, z, 2) MEANC(A, w, 3)
    MEANC(B, x, 0) MEANC(B, y, 1) MEANC(B, z, 2) MEANC(B, w, 3)

    #pragma unroll 1
    for (int it = 0; it < 3; ++it) {
        v2f svA = V0A * V0A;
        svA = pkfma(V1A, V1A, svA); svA = pkfma(V2A, V2A, svA);
        svA = pkfma(V3A, V3A, svA);
        float ssA = swz16_add(svA.x + svA.y);
        v2f svB = V0B * V0B;
        svB = pkfma(V1B, V1B, svB); svB = pkfma(V2B, V2B, svB);
        svB = pkfma(V3B, V3B, svB);
        float ssB = swz16_add(svB.x + svB.y);
        float invA = frcp(fmaxf(sqrtf(ssA), 1e-12f));
        float invB = frcp(fmaxf(sqrtf(ssB), 1e-12f));

        float E0A = __expf(DOTP(A, 0) * invA);
        float E0B = __expf(DOTP(B, 0) * invB);
        float E1A = __expf(DOTP(A, 1) * invA);
        float E1B = __expf(DOTP(B, 1) * invB);
        float E2A = __expf(DOTP(A, 2) * invA);
        float E2B = __expf(DOTP(B, 2) * invB);
        float E3A = __expf(DOTP(A, 3) * invA);
        float E3B = __expf(DOTP(B, 3) * invB);
        float E4A = has5 ? __expf(DOTP(A, 4) * invA) : 0.0f;
        float E4B = has5 ? __expf(DOTP(B, 4) * invB) : 0.0f;
        float ssumA = dpp_add16(((E0A + E1A) + (E2A + E3A)) + E4A);
        float ssumB = dpp_add16(((E0B + E1B) + (E2B + E3B)) + E4B);
        float rsA = frcp(ssumA);
        float rsB = frcp(ssumB);

        v2f e0A = {E0A, E0A}, e1A = {E1A, E1A}, e2A = {E2A, E2A};
        v2f e3A = {E3A, E3A}, e4A = {E4A, E4A};
        v2f e0B = {E0B, E0B}, e1B = {E1B, E1B}, e2B = {E2B, E2B};
        v2f e3B = {E3B, E3B}, e4B = {E4B, E4B};
        UPDC(A, x, 0) UPDC(A, y, 1) UPDC(A, z, 2) UPDC(A, w, 3)
        UPDC(B, x, 0) UPDC(B, y, 1) UPDC(B, z, 2) UPDC(B, w, 3)
    }

    v2f svA = V0A * V0A;
    svA = pkfma(V1A, V1A, svA); svA = pkfma(V2A, V2A, svA);
    svA = pkfma(V3A, V3A, svA);
    float ssA = swz16_add(svA.x + svA.y);
    float scaleA = sqrtf(ssA) * frcp(1.0f + ssA);
    v2f svB = V0B * V0B;
    svB = pkfma(V1B, V1B, svB); svB = pkfma(V2B, V2B, svB);
    svB = pkfma(V3B, V3B, svB);
    float ssB = swz16_add(svB.x + svB.y);
    float scaleB = sqrtf(ssB) * frcp(1.0f + ssB);

    if (sc < 8) {
        const int tg = tt * 32 + o2 * 16 + jh * 8 + sc;
        v2f a0A = (sc & 4) ? V2A : V0A;
        v2f a1A = (sc & 4) ? V3A : V1A;
        v2f b0A = (sc & 2) ? a1A : a0A;
        float resA = ((sc & 1) ? b0A.y : b0A.x) * scaleA;
        out[((bb * 256 + tg) * 32 + h) * 32 + w0 + pA] = resA;

        v2f a0B = (sc & 4) ? V2B : V0B;
        v2f a1B = (sc & 4) ? V3B : V1B;
        v2f b0B = (sc & 2) ? a1B : a0B;
        float resB = ((sc & 1) ? b0B.y : b0B.x) * scaleB;
        out[((bb * 256 + tg) * 32 + h) * 32 + w0 + pB] = resB;
    }
}

// ---- fallback (tiny ws): self-contained (v9 verbatim) ----
__global__ __launch_bounds__(256, 1)
void capsule_fb(const float* __restrict__ x, const float* __restrict__ Wraw,
                float* __restrict__ out) {
    __shared__ float patch[9 * 128];
    const int blk = blockIdx.x;
    const int b = blk >> 10, h = (blk >> 5) & 31, w = blk & 31;
    const int t = threadIdx.x;

    const float* xb = x + b * (128 * 32 * 32);
    for (int idx = t; idx < 1152; idx += 256) {
        int c = idx / 9, ij = idx - c * 9;
        int di = ij / 3, dj = ij - di * 3;
        int hh = h + di - 1, ww = w + dj - 1;
        float v = 0.0f;
        if ((unsigned)hh < 32u && (unsigned)ww < 32u)
            v = xb[(c * 32 + hh) * 32 + ww];
        patch[ij * 128 + c] = v;
    }
    __syncthreads();

    float u[72];
    #pragma unroll
    for (int ij = 0; ij < 9; ++ij) {
        float wr[16];
        #pragma unroll
        for (int m = 0; m < 16; ++m) wr[m] = Wraw[(t * 16 + m) * 9 + ij];
        #pragma unroll
        for (int g = 0; g < 8; ++g) {
            float acc = 0.0f;
            #pragma unroll
            for (int m = 0; m < 16; ++m)
                acc = fmaf(patch[ij * 128 + g * 16 + m], wr[m], acc);
            u[g * 9 + ij] = acc;
        }
    }

    float v = 0.0f;
    #pragma unroll
    for (int n = 0; n < 72; ++n) v += u[n];
    v *= (1.0f / 72.0f);
    #pragma unroll 1
    for (int it = 0; it < 3; ++it) {
        float sg = dpp_add16(v * v);
        float vn = v * frcp(fmaxf(sqrtf(sg), 1e-12f));
        float ssum = 0.0f, vacc = 0.0f;
        #pragma unroll
        for (int n = 0; n < 72; ++n) {
            float pp = dpp_add16(u[n] * vn);
            float e = __expf(pp);
            ssum += e;
            vacc = fmaf(e, u[n], vacc);
        }
        v = vacc * frcp(ssum);
    }
    float sg = dpp_add16(v * v);
    float res = v * sqrtf(sg) * frcp(1.0f + sg);
    out[((b * 256 + t) * 32 + h) * 32 + w] = res;
}

extern "C" void kernel_launch(void* const* d_in, const int* in_sizes, int n_in,
                              void* d_out, int out_size, void* d_ws, size_t ws_size,
                              hipStream_t stream) {
    const float* x = (const float*)d_in[0];   // [2,128,32,32]
    const float* W = (const float*)d_in[1];   // [16,16,16,3,3]
    float* out = (float*)d_out;               // [2,256,32,32]
    i4* xP = (i4*)d_ws;                       // 1 MB
    unsigned short* Wbf = (unsigned short*)((char*)d_ws + 1048576);  // 144 KB

    const size_t need = 1048576 + (size_t)WBF_ELEMS * 2;
    if (ws_size >= need) {
        prep2_kernel<<<352, 256, 0, stream>>>(x, W, xP, Wbf);
        capsule_v17<<<4096, 128, 0, stream>>>(xP, (const i4*)Wbf, out);
    } else {
        capsule_fb<<<2048, 256, 0, stream>>>(x, W, out);
    }
}

// Round 12
// 79.650 us; speedup vs baseline: 1.1445x; 1.0430x over previous
//
#include <hip/hip_runtime.h>

// CapsuleConv2d, MI355X gfx950. ALL I/O FP32.
// B=2, C_in=128 (G=8 x M=16), 32x32, 3x3 pad 1, O=16, L=16 -> C_out=256.
// k-means (dot) routing 3 iters + squash.
//
// v18 resubmit (round-11 failure was infra: pytest core dump with 82s npz
// push times and a cold container; this exact source passed in round 6 at
// 79.6us / absmax 4.88e-4). Session-best structure:
//  - prep2 pre-packs xP (A-frag bf16 hi/lo, 16B i4 loads) + Wbf (B-frags).
//  - capsule phase 1 = pure loads + 3 MFMA/ij + CWR (zero pack VALU).
//  - phase 2 = v9-verbatim wave-per-pixel routing (latency-bound floor;
//    v10..v17 matrix bracketed all TLP/ILP/VALU levers at 79.5-91us).

typedef float v2f __attribute__((ext_vector_type(2)));
typedef int   i4  __attribute__((ext_vector_type(4)));
typedef short bh8 __attribute__((ext_vector_type(8)));
typedef float f16v __attribute__((ext_vector_type(16)));

#define STR 34                          // u LDS row stride (floats)
#define WBF_ELEMS 73728                 // Wbf u16 count (144 KB)

#define DPP_ADD(a, ctrl)                                                     \
  a += __int_as_float(__builtin_amdgcn_update_dpp(                           \
          0, __float_as_int(a), ctrl, 0xF, 0xF, true))

__device__ __forceinline__ float dpp_add16(float x) {
    float s = x;
    DPP_ADD(s, 0x128); DPP_ADD(s, 0x124); DPP_ADD(s, 0x122); DPP_ADD(s, 0x121);
    return s;
}

__device__ __forceinline__ float swz16_add(float x) {
    int y = __builtin_amdgcn_ds_swizzle(__float_as_int(x), 0x401F);
    return x + __int_as_float(y);
}

__device__ __forceinline__ float frcp(float x) {
    return __builtin_amdgcn_rcpf(x);
}

__device__ __forceinline__ v2f pkfma(v2f a, v2f b, v2f c) {
    return __builtin_elementwise_fma(a, b, c);
}

// ---- prep2: blk<64 -> xP pack; blk>=64 -> Wbf pack ----
// xP i4-index = ((((b*32+h)*32+w)*8+gl)*2+half)*2+s ; 8 bf16 u16 each.
// Wbf flat idx = (((ij*8+tt)*2+s)*64 + L)*8 + j
__global__ __launch_bounds__(256)
void prep2_kernel(const float* __restrict__ x, const float* __restrict__ W,
                  i4* __restrict__ xP, unsigned short* __restrict__ Wbf) {
    const int blk = blockIdx.x;
    const int tid = threadIdx.x;
    if (blk < 64) {
        __shared__ float xs[128 * 33];
        const int b = blk >> 5, h = blk & 31;
        const float* xb = x + b * (128 * 32 * 32) + h * 32;
        #pragma unroll
        for (int k = 0; k < 16; ++k) {
            int idx = k * 256 + tid;
            int c = idx >> 5, w = idx & 31;
            xs[c * 33 + w] = xb[c * 1024 + w];
        }
        __syncthreads();
        i4* xo = xP + (b * 32 + h) * 1024;
        #pragma unroll
        for (int it = 0; it < 4; ++it) {
            int slot = it * 256 + tid;          // = w*32 + gl*4 + hf*2 + s
            int s  = slot & 1;
            int hf = (slot >> 1) & 1;
            int gl = (slot >> 2) & 7;
            int w  = slot >> 5;
            int c0 = gl * 16 + hf * 8;
            float f0 = xs[(c0 + 0) * 33 + w], f1 = xs[(c0 + 1) * 33 + w];
            float f2 = xs[(c0 + 2) * 33 + w], f3 = xs[(c0 + 3) * 33 + w];
            float f4 = xs[(c0 + 4) * 33 + w], f5 = xs[(c0 + 5) * 33 + w];
            float f6 = xs[(c0 + 6) * 33 + w], f7 = xs[(c0 + 7) * 33 + w];
            unsigned b0 = __float_as_uint(f0), b1 = __float_as_uint(f1);
            unsigned b2 = __float_as_uint(f2), b3 = __float_as_uint(f3);
            unsigned b4 = __float_as_uint(f4), b5 = __float_as_uint(f5);
            unsigned b6 = __float_as_uint(f6), b7 = __float_as_uint(f7);
            i4 pk;
            if (s == 0) {
                pk.x = (int)((b0 >> 16) | (b1 & 0xFFFF0000u));
                pk.y = (int)((b2 >> 16) | (b3 & 0xFFFF0000u));
                pk.z = (int)((b4 >> 16) | (b5 & 0xFFFF0000u));
                pk.w = (int)((b6 >> 16) | (b7 & 0xFFFF0000u));
            } else {
                unsigned l0 = __float_as_uint(f0 - __uint_as_float(b0 & 0xFFFF0000u));
                unsigned l1 = __float_as_uint(f1 - __uint_as_float(b1 & 0xFFFF0000u));
                unsigned l2 = __float_as_uint(f2 - __uint_as_float(b2 & 0xFFFF0000u));
                unsigned l3 = __float_as_uint(f3 - __uint_as_float(b3 & 0xFFFF0000u));
                unsigned l4 = __float_as_uint(f4 - __uint_as_float(b4 & 0xFFFF0000u));
                unsigned l5 = __float_as_uint(f5 - __uint_as_float(b5 & 0xFFFF0000u));
                unsigned l6 = __float_as_uint(f6 - __uint_as_float(b6 & 0xFFFF0000u));
                unsigned l7 = __float_as_uint(f7 - __uint_as_float(b7 & 0xFFFF0000u));
                pk.x = (int)((l0 >> 16) | (l1 & 0xFFFF0000u));
                pk.y = (int)((l2 >> 16) | (l3 & 0xFFFF0000u));
                pk.z = (int)((l4 >> 16) | (l5 & 0xFFFF0000u));
                pk.w = (int)((l6 >> 16) | (l7 & 0xFFFF0000u));
            }
            xo[slot] = pk;
        }
    } else {
        int idx = (blk - 64) * 256 + tid;     // 0..73727
        int j  = idx & 7;
        int L  = (idx >> 3) & 63;
        int s  = (idx >> 9) & 1;
        int tt = (idx >> 10) & 7;
        int ij = idx >> 13;
        int k  = (L >> 5) * 8 + j;
        int t  = tt * 32 + (L & 31);
        float wv = W[(t * 16 + k) * 9 + ij];
        unsigned bits = __float_as_uint(wv);
        unsigned hib  = bits & 0xFFFF0000u;
        unsigned short val;
        if (s == 0) val = (unsigned short)(hib >> 16);
        else {
            float lo = wv - __uint_as_float(hib);
            val = (unsigned short)(__float_as_uint(lo) >> 16);
        }
        Wbf[idx] = val;
    }
}

// ---- phase-1 macro: one ij = load A, load B, 3 MFMA, 16 CWR ----
#define CWR(REG, IJ)                                                         \
    uLds[wroff + STR * ((((REG) >> 2) * 72) + (((REG) & 3) * 9) + (IJ))] =   \
        acc[(REG)];

#define ONEIJ(IJ) {                                                          \
    const int di = (IJ) / 3, dj = (IJ) % 3;                                  \
    const int hh = h + di - 1;                                               \
    const bool hok = (unsigned)hh < 32u;                                     \
    const int hhc = hok ? hh : 0;                                            \
    const int ww = w0 + pl + dj - 1;                                         \
    const bool ok = hok && ((unsigned)ww < 32u);                             \
    const int wwc = ok ? ww : 0;                                             \
    const int slot = (((bb * 32 + hhc) * 32 + wwc) * 8 + gl) * 2 + half;     \
    i4 ah = xpi4[slot * 2];                                                  \
    i4 al = xpi4[slot * 2 + 1];                                              \
    i4 bh = bfr[((IJ) * 8 + tt) * 128 + lane];                               \
    i4 bl = bfr[((IJ) * 8 + tt) * 128 + 64 + lane];                          \
    const i4 z_ = {0, 0, 0, 0};                                              \
    ah = ok ? ah : z_;                                                       \
    al = ok ? al : z_;                                                       \
    bh8 aHi = __builtin_bit_cast(bh8, ah);                                   \
    bh8 aLo = __builtin_bit_cast(bh8, al);                                   \
    bh8 bHi = __builtin_bit_cast(bh8, bh);                                   \
    bh8 bLo = __builtin_bit_cast(bh8, bl);                                   \
    f16v acc = {0.f,0.f,0.f,0.f,0.f,0.f,0.f,0.f,                             \
                0.f,0.f,0.f,0.f,0.f,0.f,0.f,0.f};                            \
    acc = __builtin_amdgcn_mfma_f32_32x32x16_bf16(aHi, bLo, acc, 0, 0, 0);   \
    acc = __builtin_amdgcn_mfma_f32_32x32x16_bf16(aLo, bHi, acc, 0, 0, 0);   \
    acc = __builtin_amdgcn_mfma_f32_32x32x16_bf16(aHi, bHi, acc, 0, 0, 0);   \
    CWR(0, IJ)  CWR(1, IJ)  CWR(2, IJ)  CWR(3, IJ)                           \
    CWR(4, IJ)  CWR(5, IJ)  CWR(6, IJ)  CWR(7, IJ)                           \
    CWR(8, IJ)  CWR(9, IJ)  CWR(10, IJ) CWR(11, IJ)                          \
    CWR(12, IJ) CWR(13, IJ) CWR(14, IJ) CWR(15, IJ) }

// ---- phase-2 macros (v9 verbatim) ----
#define LROW(K)                                                              \
  { const v2f* r2_ = (const v2f*)(rb + (K) * 16 * STR);                      \
    U##K##0 = r2_[0]; U##K##1 = r2_[1]; U##K##2 = r2_[2]; U##K##3 = r2_[3]; }

#define DOTR(K)                                                              \
  ({ v2f d_ = U##K##0 * V0;                                                  \
     d_ = pkfma(U##K##1, V1, d_); d_ = pkfma(U##K##2, V2, d_);               \
     d_ = pkfma(U##K##3, V3, d_); swz16_add(d_.x + d_.y); })

#define MEANJ(J)                                                             \
  { v2f s_ = (U0##J + U1##J) + (U2##J + U3##J) + U4##J;                      \
    V##J.x = dpp_add16(s_.x) * (1.0f / 72.0f);                               \
    V##J.y = dpp_add16(s_.y) * (1.0f / 72.0f); }

#define UPDJ(J)                                                              \
  { v2f pv_ = e0v * U0##J;                                                   \
    pv_ = pkfma(e1v, U1##J, pv_); pv_ = pkfma(e2v, U2##J, pv_);              \
    pv_ = pkfma(e3v, U3##J, pv_); pv_ = pkfma(e4v, U4##J, pv_);              \
    V##J.x = dpp_add16(pv_.x) * rs;                                          \
    V##J.y = dpp_add16(pv_.y) * rs; }

// ---- main kernel: 4096 blocks, 4 pixels x 32 t, pure-load phase 1 ----
__global__ __launch_bounds__(256, 4)
void capsule_v18(const i4* __restrict__ xpi4, const i4* __restrict__ bfr,
                 float* __restrict__ out) {
    __shared__ float uLds[4 * 72 * STR];     // 38.25 KB -> 4 blocks/CU
    const int blk = blockIdx.x;              // 4096 = tt(8) x bb(2) x h(32) x wq(8)
    const int tt  = blk & 7;
    const int q   = blk >> 3;
    const int bb  = q >> 8;
    const int r   = q & 255;
    const int h   = r >> 3;
    const int w0  = (r & 7) << 2;
    const int tid = threadIdx.x;

    // ---- phase 1: pure-load A/B frags, MFMA, CWR (all 16 regs) ----
    {
        const int lane = tid & 63;
        const int wv   = tid >> 6;
        const int pl   = (lane & 31) >> 3;   // pixel within quad
        const int gl   = lane & 7;           // group
        const int half = lane >> 5;          // k-half
        const int tl   = lane & 31;          // C col
        const int wroff = tl + STR * 9 * 4 * half;

        if      (wv == 0) { ONEIJ(0) ONEIJ(4) ONEIJ(8) }
        else if (wv == 1) { ONEIJ(1) ONEIJ(5) }
        else if (wv == 2) { ONEIJ(2) ONEIJ(6) }
        else              { ONEIJ(3) ONEIJ(7) }
    }
    __syncthreads();

    // ---- phase 2: routing, v9 verbatim; wave = pixel (p = tid>>6) ----
    const int p  = tid >> 6;
    const int i6 = tid & 63;
    const int o2 = i6 >> 5;
    const int jh = (i6 >> 4) & 1;
    const int sc = i6 & 15;
    const bool has5 = (sc < 8);
    const float* rb = uLds + (p * 72 + sc) * STR + o2 * 16 + jh * 8;

    v2f U00, U01, U02, U03;
    v2f U10, U11, U12, U13;
    v2f U20, U21, U22, U23;
    v2f U30, U31, U32, U33;
    v2f U40, U41, U42, U43;
    U40 = U41 = U42 = U43 = (v2f){0.0f, 0.0f};
    LROW(0) LROW(1) LROW(2) LROW(3)
    if (has5) LROW(4)

    v2f V0, V1, V2, V3;
    MEANJ(0) MEANJ(1) MEANJ(2) MEANJ(3)

    #pragma unroll 1
    for (int it = 0; it < 3; ++it) {
        v2f ssv = V0 * V0;
        ssv = pkfma(V1, V1, ssv); ssv = pkfma(V2, V2, ssv);
        ssv = pkfma(V3, V3, ssv);
        float ss = swz16_add(ssv.x + ssv.y);
        float inv = frcp(fmaxf(sqrtf(ss), 1e-12f));

        float E0 = __expf(DOTR(0) * inv);
        float E1 = __expf(DOTR(1) * inv);
        float E2 = __expf(DOTR(2) * inv);
        float E3 = __expf(DOTR(3) * inv);
        float E4 = has5 ? __expf(DOTR(4) * inv) : 0.0f;
        float ssum = dpp_add16(((E0 + E1) + (E2 + E3)) + E4);
        float rs = frcp(ssum);

        v2f e0v = {E0, E0}, e1v = {E1, E1}, e2v = {E2, E2};
        v2f e3v = {E3, E3}, e4v = {E4, E4};
        UPDJ(0) UPDJ(1) UPDJ(2) UPDJ(3)
    }

    v2f ssv = V0 * V0;
    ssv = pkfma(V1, V1, ssv); ssv = pkfma(V2, V2, ssv);
    ssv = pkfma(V3, V3, ssv);
    float ss = swz16_add(ssv.x + ssv.y);
    float scale = sqrtf(ss) * frcp(1.0f + ss);

    v2f aa0 = (sc & 4) ? V2 : V0;
    v2f aa1 = (sc & 4) ? V3 : V1;
    v2f bb0 = (sc & 2) ? aa1 : aa0;
    float res = ((sc & 1) ? bb0.y : bb0.x) * scale;
    if (sc < 8) {
        int tg = tt * 32 + o2 * 16 + jh * 8 + sc;   // global channel
        out[((bb * 256 + tg) * 32 + h) * 32 + w0 + p] = res;
    }
}

// ---- fallback (tiny ws): self-contained ----
__global__ __launch_bounds__(256, 1)
void capsule_fb(const float* __restrict__ x, const float* __restrict__ Wraw,
                float* __restrict__ out) {
    __shared__ float patch[9 * 128];
    const int blk = blockIdx.x;
    const int b = blk >> 10, h = (blk >> 5) & 31, w = blk & 31;
    const int t = threadIdx.x;

    const float* xb = x + b * (128 * 32 * 32);
    for (int idx = t; idx < 1152; idx += 256) {
        int c = idx / 9, ij = idx - c * 9;
        int di = ij / 3, dj = ij - di * 3;
        int hh = h + di - 1, ww = w + dj - 1;
        float v = 0.0f;
        if ((unsigned)hh < 32u && (unsigned)ww < 32u)
            v = xb[(c * 32 + hh) * 32 + ww];
        patch[ij * 128 + c] = v;
    }
    __syncthreads();

    float u[72];
    #pragma unroll
    for (int ij = 0; ij < 9; ++ij) {
        float wr[16];
        #pragma unroll
        for (int m = 0; m < 16; ++m) wr[m] = Wraw[(t * 16 + m) * 9 + ij];
        #pragma unroll
        for (int g = 0; g < 8; ++g) {
            float acc = 0.0f;
            #pragma unroll
            for (int m = 0; m < 16; ++m)
                acc = fmaf(patch[ij * 128 + g * 16 + m], wr[m], acc);
            u[g * 9 + ij] = acc;
        }
    }

    float v = 0.0f;
    #pragma unroll
    for (int n = 0; n < 72; ++n) v += u[n];
    v *= (1.0f / 72.0f);
    #pragma unroll 1
    for (int it = 0; it < 3; ++it) {
        float sg = dpp_add16(v * v);
        float vn = v * frcp(fmaxf(sqrtf(sg), 1e-12f));
        float ssum = 0.0f, vacc = 0.0f;
        #pragma unroll
        for (int n = 0; n < 72; ++n) {
            float pp = dpp_add16(u[n] * vn);
            float e = __expf(pp);
            ssum += e;
            vacc = fmaf(e, u[n], vacc);
        }
        v = vacc * frcp(ssum);
    }
    float sg = dpp_add16(v * v);
    float res = v * sqrtf(sg) * frcp(1.0f + sg);
    out[((b * 256 + t) * 32 + h) * 32 + w] = res;
}

extern "C" void kernel_launch(void* const* d_in, const int* in_sizes, int n_in,
                              void* d_out, int out_size, void* d_ws, size_t ws_size,
                              hipStream_t stream) {
    const float* x = (const float*)d_in[0];   // [2,128,32,32]
    const float* W = (const float*)d_in[1];   // [16,16,16,3,3]
    float* out = (float*)d_out;               // [2,256,32,32]
    i4* xP = (i4*)d_ws;                       // 1 MB
    unsigned short* Wbf = (unsigned short*)((char*)d_ws + 1048576);  // 144 KB

    const size_t need = 1048576 + (size_t)WBF_ELEMS * 2;
    if (ws_size >= need) {
        prep2_kernel<<<352, 256, 0, stream>>>(x, W, xP, Wbf);
        capsule_v18<<<4096, 256, 0, stream>>>(xP, (const i4*)Wbf, out);
    } else {
        capsule_fb<<<2048, 256, 0, stream>>>(x, W, out);
    }
}